// Round 12
// baseline (252.632 us; speedup 1.0000x reference)
//
#include <hip/hip_runtime.h>
#include <hip/hip_bf16.h>

typedef __bf16 bf16x8 __attribute__((ext_vector_type(8)));
typedef float f32x4 __attribute__((ext_vector_type(4)));
typedef float f32x16 __attribute__((ext_vector_type(16)));
typedef unsigned short u16x8 __attribute__((ext_vector_type(8)));
typedef unsigned short u16x4 __attribute__((ext_vector_type(4)));

#define HB 16
#define TT 2048
#define CCH 1024
#define DD 64

#define AS1 __attribute__((address_space(1)))
#define AS3 __attribute__((address_space(3)))
#define GL16(gp, lp) __builtin_amdgcn_global_load_lds((const AS1 void*)(gp), (AS3 void*)(lp), 16, 0, 0)

__device__ __forceinline__ unsigned short f2bf(float f) {
  union { __hip_bfloat16 h; unsigned short u; } cv;
  cv.h = __float2bfloat16(f);
  return cv.u;
}

// packed bf16 pair: D[15:0]=bf16(lo), D[31:16]=bf16(hi)
__device__ __forceinline__ unsigned pack2(float lo, float hi) {
  unsigned r;
  asm("v_cvt_pk_bf16_f32 %0, %1, %2" : "=v"(r) : "v"(lo), "v"(hi));
  return r;
}

__device__ __forceinline__ f32x4 mfma16(bf16x8 a, bf16x8 b, f32x4 c) {
  return __builtin_amdgcn_mfma_f32_16x16x32_bf16(a, b, c, 0, 0, 0);
}
__device__ __forceinline__ f32x16 mfma32(bf16x8 a, bf16x8 b, f32x16 c) {
  return __builtin_amdgcn_mfma_f32_32x32x16_bf16(a, b, c, 0, 0, 0);
}

__device__ __forceinline__ f32x16 zero16() {
  f32x16 z;
  #pragma unroll
  for (int r = 0; r < 16; ++r) z[r] = 0.f;
  return z;
}

// ---------------- conversion kernels ----------------

__global__ __launch_bounds__(256) void cvt_f32_bf16(const float* __restrict__ in,
                                                    unsigned short* __restrict__ out,
                                                    int n4) {
  int i = blockIdx.x * 256 + threadIdx.x;
  if (i >= n4) return;
  float4 v = reinterpret_cast<const float4*>(in)[i];
  u16x4 o;
  o.x = f2bf(v.x); o.y = f2bf(v.y); o.z = f2bf(v.z); o.w = f2bf(v.w);
  *reinterpret_cast<u16x4*>(out + (size_t)i * 4) = o;
}

// w: [1024 x N] fp32  ->  wt: [N x 1024] bf16 (transposed)
__global__ __launch_bounds__(256) void transpose_cvt(const float* __restrict__ w,
                                                     unsigned short* __restrict__ wt,
                                                     int N) {
  __shared__ unsigned short t[32][33];
  int nb = blockIdx.x * 32, kb = blockIdx.y * 32;
  int tx = threadIdx.x & 31, ty = threadIdx.x >> 5;  // ty 0..7
  #pragma unroll
  for (int r = 0; r < 32; r += 8)
    t[ty + r][tx] = f2bf(w[(size_t)(kb + ty + r) * N + nb + tx]);
  __syncthreads();
  #pragma unroll
  for (int r = 0; r < 32; r += 8)
    wt[(size_t)(nb + ty + r) * 1024 + kb + tx] = t[tx][ty + r];
}

// ---------------- GEMM (m97 structure): C = A @ Bt^T (+bias) ----------------
// 1-D grid + XCD-bijective swizzle (unchanged from round 7).

template <int EPI>
__global__ __launch_bounds__(256) void gemm_bf16(
    const unsigned short* __restrict__ A,
    const unsigned short* __restrict__ Bt,
    const float* __restrict__ bias,
    float* __restrict__ outf,
    unsigned short* __restrict__ qb,
    unsigned short* __restrict__ kb,
    unsigned short* __restrict__ vt,
    int nbx, int wpx) {  // nbx = n-blocks, wpx = nwg/8
  __shared__ unsigned short As[8192];  // [128][64] linear
  __shared__ unsigned short Bs[8192];
  const int bid = blockIdx.x;
  const int work = (bid & 7) * wpx + (bid >> 3);
  const int m0 = (work / nbx) * 128, n0 = (work % nbx) * 128;
  const int tid = threadIdx.x;
  const int lane = tid & 63;
  const int wid = tid >> 6;
  const int r16 = lane & 15, g = lane >> 4;
  const int wm = wid >> 1, wn = wid & 1;
  const int srow = tid >> 3;                 // 0..31 (+32 per instr)
  const int schx = (tid & 7) ^ (srow & 7);   // XOR-swizzled source chunk

  f32x4 acc[4][4];
  #pragma unroll
  for (int i = 0; i < 4; ++i)
    #pragma unroll
    for (int j = 0; j < 4; ++j) acc[i][j] = (f32x4){0.f, 0.f, 0.f, 0.f};

  const int rx = r16 & 7;

  for (int kt = 0; kt < 1024; kt += 64) {
    #pragma unroll
    for (int i = 0; i < 4; ++i) {
      const int row = i * 32 + srow;
      GL16(A + (size_t)(m0 + row) * 1024 + kt + schx * 8, As + i * 2048 + tid * 8);
    }
    #pragma unroll
    for (int i = 0; i < 4; ++i) {
      const int row = i * 32 + srow;
      GL16(Bt + (size_t)(n0 + row) * 1024 + kt + schx * 8, Bs + i * 2048 + tid * 8);
    }
    __syncthreads();
    #pragma unroll
    for (int h = 0; h < 2; ++h) {
      bf16x8 af[4], bfr[4];
      #pragma unroll
      for (int i = 0; i < 4; ++i)
        af[i] = *reinterpret_cast<const bf16x8*>(
            &As[(wm * 64 + i * 16 + r16) * 64 + ((g + 4 * h) ^ rx) * 8]);
      #pragma unroll
      for (int j = 0; j < 4; ++j)
        bfr[j] = *reinterpret_cast<const bf16x8*>(
            &Bs[(wn * 64 + j * 16 + r16) * 64 + ((g + 4 * h) ^ rx) * 8]);
      #pragma unroll
      for (int i = 0; i < 4; ++i)
        #pragma unroll
        for (int j = 0; j < 4; ++j)
          acc[i][j] = mfma16(af[i], bfr[j], acc[i][j]);
    }
    __syncthreads();
  }

  #pragma unroll
  for (int i = 0; i < 4; ++i) {
    #pragma unroll
    for (int j = 0; j < 4; ++j) {
      const int n = n0 + wn * 64 + j * 16 + r16;
      const int mbase = m0 + wm * 64 + i * 16 + g * 4;
      const float bi = bias[n];
      if (EPI == 1) {
        #pragma unroll
        for (int r = 0; r < 4; ++r)
          outf[(size_t)(mbase + r) * 1024 + n] = acc[i][j][r] + bi;
      } else {
        const int which = n >> 10;
        const int cc2 = n & 1023;
        const int h = cc2 >> 6, d = cc2 & 63;
        const int b = mbase >> 11, t = mbase & 2047;
        if (which == 2) {
          u16x4 o;
          #pragma unroll
          for (int r = 0; r < 4; ++r) o[r] = f2bf(acc[i][j][r] + bi);
          *reinterpret_cast<u16x4*>(
              &vt[(((size_t)b * HB + h) * DD + d) * TT + t]) = o;
        } else {
          unsigned short* dst = (which == 0) ? qb : kb;
          // q folded scale: 1/sqrt(64) * log2(e)  (exp2-domain softmax)
          const float sc = (which == 0) ? 0.18033688011112042f : 1.0f;
          #pragma unroll
          for (int r = 0; r < 4; ++r)
            dst[(((size_t)b * HB + h) * TT + (t + r)) * DD + d] =
                f2bf((acc[i][j][r] + bi) * sc);
        }
      }
    }
  }
}

// ---------------- flash attention (barrier-free, LDS-free, direct-L2) --------
// K/V per head = 512 KB, L2-resident per XCD (r7: FETCH 24.7 MB proves it).
// Guide common-mistake #7: don't LDS-stage L2-fit data. Each wave = one
// independent 32-q strip; K/V fragments read straight from global with 16B
// vector loads; NO barriers, NO LDS -> waves drift into different phases and
// cover each other's load latency. 4096 waves; launch_bounds(256,4) forces
// VGPR<=128 => 4 waves/SIMD (2x round-10/11).
// Strip s: q in [32s, 32s+32), nt = s/2+1 kv-64 tiles. Block bundles strips
// {jb, 31-jb, 32+jb, 63-jb} -> uniform 66 tiles/block. XCD swizzle: all 16
// blocks of a head land on one XCD.
// Math (mfma32 swapped QK^T, permlane32_swap P-path) identical to verified
// round-10 kernel; the XOR LDS swizzle drops out (it was a staging artifact).

__global__ __launch_bounds__(256, 4) void attn_kernel(
    const unsigned short* __restrict__ qg_,
    const unsigned short* __restrict__ kg_,
    const unsigned short* __restrict__ vtg_,
    unsigned short* __restrict__ yb) {
  const int bid = blockIdx.x;
  const int work = (bid & 7) * 128 + (bid >> 3);
  const int bh = work >> 4;       // head index 0..63
  const int jb = work & 15;       // 0..15
  const int wid = threadIdx.x >> 6;
  const int lane = threadIdx.x & 63;
  const int l31 = lane & 31, h = lane >> 5;
  const int s = (wid == 0) ? jb : (wid == 1) ? (31 - jb)
              : (wid == 2) ? (32 + jb) : (63 - jb);
  const unsigned short* __restrict__ Q = qg_ + (size_t)bh * TT * DD;
  const unsigned short* __restrict__ K = kg_ + (size_t)bh * TT * DD;
  const unsigned short* __restrict__ Vt = vtg_ + (size_t)bh * DD * TT;
  const int b = bh >> 4, hd = bh & 15;

  const int q = 32 * s + l31;     // this lane's q row
  const int nt = (s >> 1) + 1;    // kv-64 tiles for this strip

  bf16x8 qf[4];
  #pragma unroll
  for (int c = 0; c < 4; ++c)
    qf[c] = *reinterpret_cast<const bf16x8*>(&Q[(size_t)q * DD + c * 16 + h * 8]);

  // per-lane loop-invariant bases
  const unsigned short* __restrict__ K0 = K + (size_t)l31 * DD + h * 8;
  const unsigned short* __restrict__ K1 = K + (size_t)(32 + l31) * DD + h * 8;
  const unsigned short* __restrict__ V0 = Vt + (size_t)l31 * TT + h * 8;
  const unsigned short* __restrict__ V1 = Vt + (size_t)(32 + l31) * TT + h * 8;

  f32x16 y0 = zero16(), y1 = zero16();
  float lp = 0.f;

  for (int t = 0; t < nt; ++t) {
    const int kvb = t * 64;

    // ---- QK: S^T[kv 0-31][q] -> z0, [kv 32-63][q] -> z1 (direct L2 reads) --
    f32x16 z0 = zero16(), z1 = zero16();
    #pragma unroll
    for (int c = 0; c < 4; ++c) {
      bf16x8 kf = *reinterpret_cast<const bf16x8*>(&K0[(size_t)kvb * DD + c * 16]);
      z0 = mfma32(kf, qf[c], z0);
    }
    #pragma unroll
    for (int c = 0; c < 4; ++c) {
      bf16x8 kf = *reinterpret_cast<const bf16x8*>(&K1[(size_t)kvb * DD + c * 16]);
      z1 = mfma32(kf, qf[c], z1);
    }

    // ---- causal mask (last tile only) ----
    if (t == nt - 1) {
      #pragma unroll
      for (int r = 0; r < 16; ++r) {
        const int kv0 = kvb + (r & 3) + 8 * (r >> 2) + 4 * h;
        if (kv0 > q) z0[r] = -1e30f;
        if (kv0 + 32 > q) z1[r] = -1e30f;
      }
    }

    // ---- m = 0 softmax: P = exp2(z); per-lane partial sum ----
    float sq[8];
    #pragma unroll
    for (int i = 0; i < 4; ++i) {
      #pragma unroll
      for (int r = 0; r < 4; ++r) {
        z0[4 * i + r] = exp2f(z0[4 * i + r]);
        z1[4 * i + r] = exp2f(z1[4 * i + r]);
      }
      sq[i] = (z0[4 * i] + z0[4 * i + 1]) + (z0[4 * i + 2] + z0[4 * i + 3]);
      sq[4 + i] = (z1[4 * i] + z1[4 * i + 1]) + (z1[4 * i + 2] + z1[4 * i + 3]);
    }
    lp += ((sq[0] + sq[1]) + (sq[2] + sq[3])) +
          ((sq[4] + sq[5]) + (sq[6] + sq[7]));

    // ---- pack P to bf16; build PV B-frags via permlane32_swap (r10 order) --
    unsigned pw[16];
    #pragma unroll
    for (int w = 0; w < 8; ++w) {
      pw[w] = pack2(z0[2 * w], z0[2 * w + 1]);
      pw[8 + w] = pack2(z1[2 * w], z1[2 * w + 1]);
    }
    #pragma unroll
    for (int kb = 0; kb < 4; ++kb) {
      asm("v_permlane32_swap_b32 %0, %1"
          : "+v"(pw[4 * kb]), "+v"(pw[4 * kb + 2]));
      asm("v_permlane32_swap_b32 %0, %1"
          : "+v"(pw[4 * kb + 1]), "+v"(pw[4 * kb + 3]));
    }

    // ---- PV: Y^T[d][q] += V^T x P^T (direct L2 reads) ----
    #pragma unroll
    for (int kb = 0; kb < 4; ++kb) {
      union { unsigned w[4]; bf16x8 v; } pf;
      pf.w[0] = pw[4 * kb];
      pf.w[1] = pw[4 * kb + 1];
      pf.w[2] = pw[4 * kb + 2];
      pf.w[3] = pw[4 * kb + 3];
      bf16x8 vf0 = *reinterpret_cast<const bf16x8*>(&V0[kvb + kb * 16]);
      y0 = mfma32(vf0, pf.v, y0);
      bf16x8 vf1 = *reinterpret_cast<const bf16x8*>(&V1[kvb + kb * 16]);
      y1 = mfma32(vf1, pf.v, y1);
    }
  }

  // ---- epilogue: reduce l across the q-lane pair; write Y ----
  lp += __shfl_xor(lp, 32);
  const float rl = 1.0f / lp;
  const size_t obase = ((size_t)b * TT + q) * CCH + hd * DD;
  #pragma unroll
  for (int g4 = 0; g4 < 4; ++g4) {
    const int d0 = 8 * g4 + 4 * h;
    unsigned w0 = pack2(y0[4 * g4] * rl, y0[4 * g4 + 1] * rl);
    unsigned w1 = pack2(y0[4 * g4 + 2] * rl, y0[4 * g4 + 3] * rl);
    *reinterpret_cast<uint2*>(&yb[obase + d0]) = make_uint2(w0, w1);
    unsigned w2 = pack2(y1[4 * g4] * rl, y1[4 * g4 + 1] * rl);
    unsigned w3 = pack2(y1[4 * g4 + 2] * rl, y1[4 * g4 + 3] * rl);
    *reinterpret_cast<uint2*>(&yb[obase + 32 + d0]) = make_uint2(w2, w3);
  }
}

// ---------------- launcher ----------------

extern "C" void kernel_launch(void* const* d_in, const int* in_sizes, int n_in,
                              void* d_out, int out_size, void* d_ws, size_t ws_size,
                              hipStream_t stream) {
  const float* x      = (const float*)d_in[0];
  const float* w_attn = (const float*)d_in[1];
  const float* b_attn = (const float*)d_in[2];
  const float* w_proj = (const float*)d_in[3];
  const float* b_proj = (const float*)d_in[4];
  float* out = (float*)d_out;
  char* ws = (char*)d_ws;

  unsigned short* xb  = (unsigned short*)(ws + 0);          // 16 MB
  unsigned short* wat = (unsigned short*)(ws + 16777216);   // 6 MB  [3072][1024]
  unsigned short* wpt = (unsigned short*)(ws + 23068672);   // 2 MB  [1024][1024]
  unsigned short* qb  = (unsigned short*)(ws + 25165824);   // 16 MB [B,H,T,D]
  unsigned short* kb  = (unsigned short*)(ws + 41943040);   // 16 MB [B,H,T,D]
  unsigned short* vt  = (unsigned short*)(ws + 58720256);   // 16 MB [B,H,D,T]
  unsigned short* yb  = (unsigned short*)(ws + 75497472);   // 16 MB [B,T,C]

  cvt_f32_bf16<<<(8192 * 1024 / 4 + 255) / 256, 256, 0, stream>>>(x, xb, 8192 * 1024 / 4);
  transpose_cvt<<<dim3(3072 / 32, 32), 256, 0, stream>>>(w_attn, wat, 3072);
  transpose_cvt<<<dim3(1024 / 32, 32), 256, 0, stream>>>(w_proj, wpt, 1024);

  // QKV GEMM: 64 m-blocks x 24 n-blocks = 1536 wg; wpx = 192
  gemm_bf16<0><<<1536, 256, 0, stream>>>(
      xb, wat, b_attn, nullptr, qb, kb, vt, 24, 192);

  attn_kernel<<<1024, 256, 0, stream>>>(qb, kb, vt, yb);

  // proj GEMM: 64 m-blocks x 8 n-blocks = 512 wg; wpx = 64
  gemm_bf16<1><<<512, 256, 0, stream>>>(
      yb, wpt, b_proj, out, nullptr, nullptr, nullptr, 8, 64);
}

// Round 13
// 204.771 us; speedup vs baseline: 1.2337x; 1.2337x over previous
//
#include <hip/hip_runtime.h>
#include <hip/hip_bf16.h>

typedef __bf16 bf16x8 __attribute__((ext_vector_type(8)));
typedef float f32x4 __attribute__((ext_vector_type(4)));
typedef float f32x16 __attribute__((ext_vector_type(16)));
typedef unsigned short u16x8 __attribute__((ext_vector_type(8)));
typedef unsigned short u16x4 __attribute__((ext_vector_type(4)));

#define HB 16
#define TT 2048
#define CCH 1024
#define DD 64

#define AS1 __attribute__((address_space(1)))
#define AS3 __attribute__((address_space(3)))
#define GL16(gp, lp) __builtin_amdgcn_global_load_lds((const AS1 void*)(gp), (AS3 void*)(lp), 16, 0, 0)

__device__ __forceinline__ unsigned short f2bf(float f) {
  union { __hip_bfloat16 h; unsigned short u; } cv;
  cv.h = __float2bfloat16(f);
  return cv.u;
}

// packed bf16 pair: D[15:0]=bf16(lo), D[31:16]=bf16(hi)
__device__ __forceinline__ unsigned pack2(float lo, float hi) {
  unsigned r;
  asm("v_cvt_pk_bf16_f32 %0, %1, %2" : "=v"(r) : "v"(lo), "v"(hi));
  return r;
}

__device__ __forceinline__ f32x4 mfma16(bf16x8 a, bf16x8 b, f32x4 c) {
  return __builtin_amdgcn_mfma_f32_16x16x32_bf16(a, b, c, 0, 0, 0);
}
__device__ __forceinline__ f32x16 mfma32(bf16x8 a, bf16x8 b, f32x16 c) {
  return __builtin_amdgcn_mfma_f32_32x32x16_bf16(a, b, c, 0, 0, 0);
}

__device__ __forceinline__ f32x16 zero16() {
  f32x16 z;
  #pragma unroll
  for (int r = 0; r < 16; ++r) z[r] = 0.f;
  return z;
}

// ---------------- conversion kernels ----------------

__global__ __launch_bounds__(256) void cvt_f32_bf16(const float* __restrict__ in,
                                                    unsigned short* __restrict__ out,
                                                    int n4) {
  int i = blockIdx.x * 256 + threadIdx.x;
  if (i >= n4) return;
  float4 v = reinterpret_cast<const float4*>(in)[i];
  u16x4 o;
  o.x = f2bf(v.x); o.y = f2bf(v.y); o.z = f2bf(v.z); o.w = f2bf(v.w);
  *reinterpret_cast<u16x4*>(out + (size_t)i * 4) = o;
}

// w: [1024 x N] fp32  ->  wt: [N x 1024] bf16 (transposed)
__global__ __launch_bounds__(256) void transpose_cvt(const float* __restrict__ w,
                                                     unsigned short* __restrict__ wt,
                                                     int N) {
  __shared__ unsigned short t[32][33];
  int nb = blockIdx.x * 32, kb = blockIdx.y * 32;
  int tx = threadIdx.x & 31, ty = threadIdx.x >> 5;  // ty 0..7
  #pragma unroll
  for (int r = 0; r < 32; r += 8)
    t[ty + r][tx] = f2bf(w[(size_t)(kb + ty + r) * N + nb + tx]);
  __syncthreads();
  #pragma unroll
  for (int r = 0; r < 32; r += 8)
    wt[(size_t)(nb + ty + r) * 1024 + kb + tx] = t[tx][ty + r];
}

// ---------------- GEMM (m97 structure): C = A @ Bt^T (+bias) ----------------
// 1-D grid + XCD-bijective swizzle (unchanged from round 7).

template <int EPI>
__global__ __launch_bounds__(256) void gemm_bf16(
    const unsigned short* __restrict__ A,
    const unsigned short* __restrict__ Bt,
    const float* __restrict__ bias,
    float* __restrict__ outf,
    unsigned short* __restrict__ qb,
    unsigned short* __restrict__ kb,
    unsigned short* __restrict__ vt,
    int nbx, int wpx) {  // nbx = n-blocks, wpx = nwg/8
  __shared__ unsigned short As[8192];  // [128][64] linear
  __shared__ unsigned short Bs[8192];
  const int bid = blockIdx.x;
  const int work = (bid & 7) * wpx + (bid >> 3);
  const int m0 = (work / nbx) * 128, n0 = (work % nbx) * 128;
  const int tid = threadIdx.x;
  const int lane = tid & 63;
  const int wid = tid >> 6;
  const int r16 = lane & 15, g = lane >> 4;
  const int wm = wid >> 1, wn = wid & 1;
  const int srow = tid >> 3;                 // 0..31 (+32 per instr)
  const int schx = (tid & 7) ^ (srow & 7);   // XOR-swizzled source chunk

  f32x4 acc[4][4];
  #pragma unroll
  for (int i = 0; i < 4; ++i)
    #pragma unroll
    for (int j = 0; j < 4; ++j) acc[i][j] = (f32x4){0.f, 0.f, 0.f, 0.f};

  const int rx = r16 & 7;

  for (int kt = 0; kt < 1024; kt += 64) {
    #pragma unroll
    for (int i = 0; i < 4; ++i) {
      const int row = i * 32 + srow;
      GL16(A + (size_t)(m0 + row) * 1024 + kt + schx * 8, As + i * 2048 + tid * 8);
    }
    #pragma unroll
    for (int i = 0; i < 4; ++i) {
      const int row = i * 32 + srow;
      GL16(Bt + (size_t)(n0 + row) * 1024 + kt + schx * 8, Bs + i * 2048 + tid * 8);
    }
    __syncthreads();
    #pragma unroll
    for (int h = 0; h < 2; ++h) {
      bf16x8 af[4], bfr[4];
      #pragma unroll
      for (int i = 0; i < 4; ++i)
        af[i] = *reinterpret_cast<const bf16x8*>(
            &As[(wm * 64 + i * 16 + r16) * 64 + ((g + 4 * h) ^ rx) * 8]);
      #pragma unroll
      for (int j = 0; j < 4; ++j)
        bfr[j] = *reinterpret_cast<const bf16x8*>(
            &Bs[(wn * 64 + j * 16 + r16) * 64 + ((g + 4 * h) ^ rx) * 8]);
      #pragma unroll
      for (int i = 0; i < 4; ++i)
        #pragma unroll
        for (int j = 0; j < 4; ++j)
          acc[i][j] = mfma16(af[i], bfr[j], acc[i][j]);
    }
    __syncthreads();
  }

  #pragma unroll
  for (int i = 0; i < 4; ++i) {
    #pragma unroll
    for (int j = 0; j < 4; ++j) {
      const int n = n0 + wn * 64 + j * 16 + r16;
      const int mbase = m0 + wm * 64 + i * 16 + g * 4;
      const float bi = bias[n];
      if (EPI == 1) {
        #pragma unroll
        for (int r = 0; r < 4; ++r)
          outf[(size_t)(mbase + r) * 1024 + n] = acc[i][j][r] + bi;
      } else {
        const int which = n >> 10;
        const int cc2 = n & 1023;
        const int h = cc2 >> 6, d = cc2 & 63;
        const int b = mbase >> 11, t = mbase & 2047;
        if (which == 2) {
          u16x4 o;
          #pragma unroll
          for (int r = 0; r < 4; ++r) o[r] = f2bf(acc[i][j][r] + bi);
          *reinterpret_cast<u16x4*>(
              &vt[(((size_t)b * HB + h) * DD + d) * TT + t]) = o;
        } else {
          unsigned short* dst = (which == 0) ? qb : kb;
          // q folded scale: 1/sqrt(64) * log2(e)  (exp2-domain softmax)
          const float sc = (which == 0) ? 0.18033688011112042f : 1.0f;
          #pragma unroll
          for (int r = 0; r < 4; ++r)
            dst[(((size_t)b * HB + h) * TT + (t + r)) * DD + d] =
                f2bf((acc[i][j][r] + bi) * sc);
        }
      }
    }
  }
}

// ---------------- flash attention (32x32 MFMA, m=0 softmax) ------------------
// Round-11 kernel body verbatim; ONLY the grid decomposition changed:
// 1024 blocks, one 128-q group per block (4 waves x 32q), nt = 2(g+1) kv-64
// tiles. Longest-first order (g = 15 - idx) so nt=32 blocks dispatch first ->
// greedy packing absorbs the triangle imbalance. 4096 waves total = 4/SIMD
// (vs round-11's 2/SIMD barrier-locked pairs) -> independent blocks at
// different phases cover each other's latency. XCD swizzle: 8 heads/XCD,
// K/V L2-resident (r7: FETCH 24.7 MB).

__global__ __launch_bounds__(256, 4) void attn_kernel(
    const unsigned short* __restrict__ qg_,
    const unsigned short* __restrict__ kg_,
    const unsigned short* __restrict__ vtg_,
    unsigned short* __restrict__ yb) {
  const int bid = blockIdx.x;
  const int xcd = bid & 7;
  const int idx = bid >> 3;              // 0..127 within XCD
  const int bh = xcd * 8 + (idx >> 4);   // 8 heads per XCD
  const int g = 15 - (idx & 15);         // q-group, longest-first
  const int tid = threadIdx.x;
  const int wid = tid >> 6;              // 0..3
  const int lane = tid & 63;
  const int l31 = lane & 31, h = lane >> 5;
  const int lx = lane & 7;               // row&7 XOR key for frag reads
  const unsigned short* Q = qg_ + (size_t)bh * TT * DD;
  const unsigned short* K = kg_ + (size_t)bh * TT * DD;
  const unsigned short* Vt = vtg_ + (size_t)bh * DD * TT;
  const int b = bh >> 4, hd = bh & 15;

  __shared__ unsigned short kbuf[2][4096];  // K tile [64 kv][64 d]
  __shared__ unsigned short vbuf[2][4096];  // V^T tile [64 d][64 kv]

  const int krow0 = tid >> 3;                 // 0..31 (+32 per instr)
  const int chx = (tid & 7) ^ (krow0 & 7);    // XOR-swizzled source chunk

#define SK(bi_, kvb_) do {                                                   \
    const unsigned short* gk_ = K + (size_t)((kvb_) + krow0) * DD + chx * 8; \
    GL16(gk_,            &kbuf[bi_][tid * 8]);                               \
    GL16(gk_ + 32 * DD,  &kbuf[bi_][2048 + tid * 8]);                        \
  } while (0)
#define SV(bi_, kvb_) do {                                                   \
    const unsigned short* gv_ = Vt + (size_t)krow0 * TT + (kvb_) + chx * 8;  \
    GL16(gv_,            &vbuf[bi_][tid * 8]);                               \
    GL16(gv_ + 32 * TT,  &vbuf[bi_][2048 + tid * 8]);                        \
  } while (0)

  const int qw = g * 128 + wid * 32;
  const int q = qw + l31;                // this lane's q row
  const int nt = 2 * (g + 1);            // kv-64 tiles for the block
  const int ntw = (qw >> 6) + 1;         // tiles this wave actually needs

  bf16x8 qf[4];
  #pragma unroll
  for (int c = 0; c < 4; ++c)
    qf[c] = *reinterpret_cast<const bf16x8*>(&Q[(size_t)q * DD + c * 16 + h * 8]);

  f32x16 y0 = zero16(), y1 = zero16();
  float lp = 0.f;

  SK(0, 0);
  SV(0, 0);
  SK(1, 64);                             // nt >= 2 always
  SV(1, 64);
  asm volatile("s_waitcnt vmcnt(4)" ::: "memory");
  __builtin_amdgcn_s_barrier();

  for (int t = 0; t < nt; ++t) {
    const unsigned short* sK = kbuf[t & 1];
    const unsigned short* sV = vbuf[t & 1];

    if (t < ntw) {
      const int kvb = t * 64;

      // ---- QK: S^T[kv 0-31][q] -> z0, [kv 32-63][q] -> z1 ----
      f32x16 z0 = zero16(), z1 = zero16();
      __builtin_amdgcn_s_setprio(1);
      #pragma unroll
      for (int c = 0; c < 4; ++c) {
        bf16x8 kf = *reinterpret_cast<const bf16x8*>(
            &sK[l31 * 64 + (((2 * c + h) ^ lx)) * 8]);
        z0 = mfma32(kf, qf[c], z0);
      }
      #pragma unroll
      for (int c = 0; c < 4; ++c) {
        bf16x8 kf = *reinterpret_cast<const bf16x8*>(
            &sK[(32 + l31) * 64 + (((2 * c + h) ^ lx)) * 8]);
        z1 = mfma32(kf, qf[c], z1);
      }
      __builtin_amdgcn_s_setprio(0);

      // ---- causal mask (only this wave's last tile) ----
      if (t == ntw - 1) {
        #pragma unroll
        for (int r = 0; r < 16; ++r) {
          const int kv0 = kvb + (r & 3) + 8 * (r >> 2) + 4 * h;
          if (kv0 > q) z0[r] = -1e30f;
          if (kv0 + 32 > q) z1[r] = -1e30f;
        }
      }

      // ---- m = 0 softmax: P = exp2(z) directly; per-lane partial sum ----
      float sq[8];
      #pragma unroll
      for (int i = 0; i < 4; ++i) {
        #pragma unroll
        for (int r = 0; r < 4; ++r) {
          z0[4 * i + r] = exp2f(z0[4 * i + r]);
          z1[4 * i + r] = exp2f(z1[4 * i + r]);
        }
        sq[i] = (z0[4 * i] + z0[4 * i + 1]) + (z0[4 * i + 2] + z0[4 * i + 3]);
        sq[4 + i] = (z1[4 * i] + z1[4 * i + 1]) + (z1[4 * i + 2] + z1[4 * i + 3]);
      }
      lp += ((sq[0] + sq[1]) + (sq[2] + sq[3])) +
            ((sq[4] + sq[5]) + (sq[6] + sq[7]));

      // ---- pack P to bf16 words; build PV B-frags via permlane32_swap ----
      unsigned pw[16];
      #pragma unroll
      for (int w = 0; w < 8; ++w) {
        pw[w] = pack2(z0[2 * w], z0[2 * w + 1]);
        pw[8 + w] = pack2(z1[2 * w], z1[2 * w + 1]);
      }
      #pragma unroll
      for (int kb = 0; kb < 4; ++kb) {
        // vdst'[32:63] = vsrc[0:31]; vsrc'[0:31] = vdst[32:63]
        asm("v_permlane32_swap_b32 %0, %1"
            : "+v"(pw[4 * kb]), "+v"(pw[4 * kb + 2]));
        asm("v_permlane32_swap_b32 %0, %1"
            : "+v"(pw[4 * kb + 1]), "+v"(pw[4 * kb + 3]));
      }

      // ---- PV: Y^T[d][q] += V^T-tile x P^T ----
      __builtin_amdgcn_s_setprio(1);
      #pragma unroll
      for (int kb = 0; kb < 4; ++kb) {
        union { unsigned w[4]; bf16x8 v; } pf;
        pf.w[0] = pw[4 * kb];
        pf.w[1] = pw[4 * kb + 1];
        pf.w[2] = pw[4 * kb + 2];
        pf.w[3] = pw[4 * kb + 3];
        bf16x8 vf0 = *reinterpret_cast<const bf16x8*>(
            &sV[l31 * 64 + (((2 * kb + h) ^ lx)) * 8]);
        y0 = mfma32(vf0, pf.v, y0);
        bf16x8 vf1 = *reinterpret_cast<const bf16x8*>(
            &sV[(32 + l31) * 64 + (((2 * kb + h) ^ lx)) * 8]);
        y1 = mfma32(vf1, pf.v, y1);
      }
      __builtin_amdgcn_s_setprio(0);
    }

    __syncthreads();  // all waves done with buf[t&1]; drains in-flight t+1
    if (t + 2 < nt) {
      SK(t & 1, (t + 2) * 64);
      SV(t & 1, (t + 2) * 64);
    }
  }

  // ---- epilogue: reduce l across the q-lane pair; write Y ----
  lp += __shfl_xor(lp, 32);
  const float rl = 1.0f / lp;
  const size_t obase = ((size_t)b * TT + q) * CCH + hd * DD;
  #pragma unroll
  for (int g4 = 0; g4 < 4; ++g4) {
    const int d0 = 8 * g4 + 4 * h;
    unsigned w0 = pack2(y0[4 * g4] * rl, y0[4 * g4 + 1] * rl);
    unsigned w1 = pack2(y0[4 * g4 + 2] * rl, y0[4 * g4 + 3] * rl);
    *reinterpret_cast<uint2*>(&yb[obase + d0]) = make_uint2(w0, w1);
    unsigned w2 = pack2(y1[4 * g4] * rl, y1[4 * g4 + 1] * rl);
    unsigned w3 = pack2(y1[4 * g4 + 2] * rl, y1[4 * g4 + 3] * rl);
    *reinterpret_cast<uint2*>(&yb[obase + 32 + d0]) = make_uint2(w2, w3);
  }
#undef SK
#undef SV
}

// ---------------- launcher ----------------

extern "C" void kernel_launch(void* const* d_in, const int* in_sizes, int n_in,
                              void* d_out, int out_size, void* d_ws, size_t ws_size,
                              hipStream_t stream) {
  const float* x      = (const float*)d_in[0];
  const float* w_attn = (const float*)d_in[1];
  const float* b_attn = (const float*)d_in[2];
  const float* w_proj = (const float*)d_in[3];
  const float* b_proj = (const float*)d_in[4];
  float* out = (float*)d_out;
  char* ws = (char*)d_ws;

  unsigned short* xb  = (unsigned short*)(ws + 0);          // 16 MB
  unsigned short* wat = (unsigned short*)(ws + 16777216);   // 6 MB  [3072][1024]
  unsigned short* wpt = (unsigned short*)(ws + 23068672);   // 2 MB  [1024][1024]
  unsigned short* qb  = (unsigned short*)(ws + 25165824);   // 16 MB [B,H,T,D]
  unsigned short* kb  = (unsigned short*)(ws + 41943040);   // 16 MB [B,H,T,D]
  unsigned short* vt  = (unsigned short*)(ws + 58720256);   // 16 MB [B,H,D,T]
  unsigned short* yb  = (unsigned short*)(ws + 75497472);   // 16 MB [B,T,C]

  cvt_f32_bf16<<<(8192 * 1024 / 4 + 255) / 256, 256, 0, stream>>>(x, xb, 8192 * 1024 / 4);
  transpose_cvt<<<dim3(3072 / 32, 32), 256, 0, stream>>>(w_attn, wat, 3072);
  transpose_cvt<<<dim3(1024 / 32, 32), 256, 0, stream>>>(w_proj, wpt, 1024);

  // QKV GEMM: 64 m-blocks x 24 n-blocks = 1536 wg; wpx = 192
  gemm_bf16<0><<<1536, 256, 0, stream>>>(
      xb, wat, b_attn, nullptr, qb, kb, vt, 24, 192);

  attn_kernel<<<1024, 256, 0, stream>>>(qb, kb, vt, yb);

  // proj GEMM: 64 m-blocks x 8 n-blocks = 512 wg; wpx = 64
  gemm_bf16<1><<<512, 256, 0, stream>>>(
      yb, wpt, b_proj, out, nullptr, nullptr, nullptr, 8, 64);
}

// Round 14
// 168.600 us; speedup vs baseline: 1.4984x; 1.2145x over previous
//
#include <hip/hip_runtime.h>
#include <hip/hip_bf16.h>

typedef __bf16 bf16x8 __attribute__((ext_vector_type(8)));
typedef float f32x4 __attribute__((ext_vector_type(4)));
typedef float f32x16 __attribute__((ext_vector_type(16)));
typedef unsigned short u16x8 __attribute__((ext_vector_type(8)));
typedef unsigned short u16x4 __attribute__((ext_vector_type(4)));

#define HB 16
#define TT 2048
#define CCH 1024
#define DD 64

#define AS1 __attribute__((address_space(1)))
#define AS3 __attribute__((address_space(3)))
#define GL16(gp, lp) __builtin_amdgcn_global_load_lds((const AS1 void*)(gp), (AS3 void*)(lp), 16, 0, 0)

__device__ __forceinline__ unsigned short f2bf(float f) {
  union { __hip_bfloat16 h; unsigned short u; } cv;
  cv.h = __float2bfloat16(f);
  return cv.u;
}

// packed bf16 pair: D[15:0]=bf16(lo), D[31:16]=bf16(hi)
__device__ __forceinline__ unsigned pack2(float lo, float hi) {
  unsigned r;
  asm("v_cvt_pk_bf16_f32 %0, %1, %2" : "=v"(r) : "v"(lo), "v"(hi));
  return r;
}

__device__ __forceinline__ f32x4 mfma16(bf16x8 a, bf16x8 b, f32x4 c) {
  return __builtin_amdgcn_mfma_f32_16x16x32_bf16(a, b, c, 0, 0, 0);
}
__device__ __forceinline__ f32x16 mfma32(bf16x8 a, bf16x8 b, f32x16 c) {
  return __builtin_amdgcn_mfma_f32_32x32x16_bf16(a, b, c, 0, 0, 0);
}

__device__ __forceinline__ f32x16 zero16() {
  f32x16 z;
  #pragma unroll
  for (int r = 0; r < 16; ++r) z[r] = 0.f;
  return z;
}

// ---------------- conversion kernels ----------------

__global__ __launch_bounds__(256) void cvt_f32_bf16(const float* __restrict__ in,
                                                    unsigned short* __restrict__ out,
                                                    int n4) {
  int i = blockIdx.x * 256 + threadIdx.x;
  if (i >= n4) return;
  float4 v = reinterpret_cast<const float4*>(in)[i];
  u16x4 o;
  o.x = f2bf(v.x); o.y = f2bf(v.y); o.z = f2bf(v.z); o.w = f2bf(v.w);
  *reinterpret_cast<u16x4*>(out + (size_t)i * 4) = o;
}

// w: [1024 x N] fp32  ->  wt: [N x 1024] bf16 (transposed)
__global__ __launch_bounds__(256) void transpose_cvt(const float* __restrict__ w,
                                                     unsigned short* __restrict__ wt,
                                                     int N) {
  __shared__ unsigned short t[32][33];
  int nb = blockIdx.x * 32, kb = blockIdx.y * 32;
  int tx = threadIdx.x & 31, ty = threadIdx.x >> 5;  // ty 0..7
  #pragma unroll
  for (int r = 0; r < 32; r += 8)
    t[ty + r][tx] = f2bf(w[(size_t)(kb + ty + r) * N + nb + tx]);
  __syncthreads();
  #pragma unroll
  for (int r = 0; r < 32; r += 8)
    wt[(size_t)(nb + ty + r) * 1024 + kb + tx] = t[tx][ty + r];
}

// ---------------- GEMM (m97 structure): C = A @ Bt^T (+bias) ----------------
// 1-D grid + XCD-bijective swizzle (unchanged from round 7).

template <int EPI>
__global__ __launch_bounds__(256) void gemm_bf16(
    const unsigned short* __restrict__ A,
    const unsigned short* __restrict__ Bt,
    const float* __restrict__ bias,
    float* __restrict__ outf,
    unsigned short* __restrict__ qb,
    unsigned short* __restrict__ kb,
    unsigned short* __restrict__ vt,
    int nbx, int wpx) {  // nbx = n-blocks, wpx = nwg/8
  __shared__ unsigned short As[8192];  // [128][64] linear
  __shared__ unsigned short Bs[8192];
  const int bid = blockIdx.x;
  const int work = (bid & 7) * wpx + (bid >> 3);
  const int m0 = (work / nbx) * 128, n0 = (work % nbx) * 128;
  const int tid = threadIdx.x;
  const int lane = tid & 63;
  const int wid = tid >> 6;
  const int r16 = lane & 15, g = lane >> 4;
  const int wm = wid >> 1, wn = wid & 1;
  const int srow = tid >> 3;                 // 0..31 (+32 per instr)
  const int schx = (tid & 7) ^ (srow & 7);   // XOR-swizzled source chunk

  f32x4 acc[4][4];
  #pragma unroll
  for (int i = 0; i < 4; ++i)
    #pragma unroll
    for (int j = 0; j < 4; ++j) acc[i][j] = (f32x4){0.f, 0.f, 0.f, 0.f};

  const int rx = r16 & 7;

  for (int kt = 0; kt < 1024; kt += 64) {
    #pragma unroll
    for (int i = 0; i < 4; ++i) {
      const int row = i * 32 + srow;
      GL16(A + (size_t)(m0 + row) * 1024 + kt + schx * 8, As + i * 2048 + tid * 8);
    }
    #pragma unroll
    for (int i = 0; i < 4; ++i) {
      const int row = i * 32 + srow;
      GL16(Bt + (size_t)(n0 + row) * 1024 + kt + schx * 8, Bs + i * 2048 + tid * 8);
    }
    __syncthreads();
    #pragma unroll
    for (int h = 0; h < 2; ++h) {
      bf16x8 af[4], bfr[4];
      #pragma unroll
      for (int i = 0; i < 4; ++i)
        af[i] = *reinterpret_cast<const bf16x8*>(
            &As[(wm * 64 + i * 16 + r16) * 64 + ((g + 4 * h) ^ rx) * 8]);
      #pragma unroll
      for (int j = 0; j < 4; ++j)
        bfr[j] = *reinterpret_cast<const bf16x8*>(
            &Bs[(wn * 64 + j * 16 + r16) * 64 + ((g + 4 * h) ^ rx) * 8]);
      #pragma unroll
      for (int i = 0; i < 4; ++i)
        #pragma unroll
        for (int j = 0; j < 4; ++j)
          acc[i][j] = mfma16(af[i], bfr[j], acc[i][j]);
    }
    __syncthreads();
  }

  #pragma unroll
  for (int i = 0; i < 4; ++i) {
    #pragma unroll
    for (int j = 0; j < 4; ++j) {
      const int n = n0 + wn * 64 + j * 16 + r16;
      const int mbase = m0 + wm * 64 + i * 16 + g * 4;
      const float bi = bias[n];
      if (EPI == 1) {
        #pragma unroll
        for (int r = 0; r < 4; ++r)
          outf[(size_t)(mbase + r) * 1024 + n] = acc[i][j][r] + bi;
      } else {
        const int which = n >> 10;
        const int cc2 = n & 1023;
        const int h = cc2 >> 6, d = cc2 & 63;
        const int b = mbase >> 11, t = mbase & 2047;
        if (which == 2) {
          u16x4 o;
          #pragma unroll
          for (int r = 0; r < 4; ++r) o[r] = f2bf(acc[i][j][r] + bi);
          *reinterpret_cast<u16x4*>(
              &vt[(((size_t)b * HB + h) * DD + d) * TT + t]) = o;
        } else {
          unsigned short* dst = (which == 0) ? qb : kb;
          // q folded scale: 1/sqrt(64) * log2(e)  (exp2-domain softmax)
          const float sc = (which == 0) ? 0.18033688011112042f : 1.0f;
          #pragma unroll
          for (int r = 0; r < 4; ++r)
            dst[(((size_t)b * HB + h) * TT + (t + r)) * DD + d] =
                f2bf((acc[i][j][r] + bi) * sc);
        }
      }
    }
  }
}

// ---------------- flash attention (32x32 MFMA, m=0 softmax) ------------------
// Round-11 kernel body verbatim; flat decomposition (one 128-q group per
// block), but with launch_bounds(256,2) — round 13's (256,4) forced VGPR
// 72->56 and spilled (the regression). 1024 blocks, 4/CU co-resident (LDS
// 32 KB allows 5/CU; VGPR 72 allows 7 waves/SIMD) -> 4 independent
// waves/SIMD at different phases cover each other's latency.
// Head-minor mapping: bh = xcd*8 + (idx&7), g = 15-(idx>>3) -> per XCD all
// 128 blocks co-resident (<= 160 slots), 8 heads/XCD K/V L2-resident.

__global__ __launch_bounds__(256, 2) void attn_kernel(
    const unsigned short* __restrict__ qg_,
    const unsigned short* __restrict__ kg_,
    const unsigned short* __restrict__ vtg_,
    unsigned short* __restrict__ yb) {
  const int bid = blockIdx.x;
  const int xcd = bid & 7;
  const int idx = bid >> 3;              // 0..127 within XCD
  const int bh = xcd * 8 + (idx & 7);    // head-minor: 8 heads per XCD
  const int g = 15 - (idx >> 3);         // q-group, longest-first
  const int tid = threadIdx.x;
  const int wid = tid >> 6;              // 0..3
  const int lane = tid & 63;
  const int l31 = lane & 31, h = lane >> 5;
  const int lx = lane & 7;               // row&7 XOR key for frag reads
  const unsigned short* Q = qg_ + (size_t)bh * TT * DD;
  const unsigned short* K = kg_ + (size_t)bh * TT * DD;
  const unsigned short* Vt = vtg_ + (size_t)bh * DD * TT;
  const int b = bh >> 4, hd = bh & 15;

  __shared__ unsigned short kbuf[2][4096];  // K tile [64 kv][64 d]
  __shared__ unsigned short vbuf[2][4096];  // V^T tile [64 d][64 kv]

  const int krow0 = tid >> 3;                 // 0..31 (+32 per instr)
  const int chx = (tid & 7) ^ (krow0 & 7);    // XOR-swizzled source chunk

#define SK(bi_, kvb_) do {                                                   \
    const unsigned short* gk_ = K + (size_t)((kvb_) + krow0) * DD + chx * 8; \
    GL16(gk_,            &kbuf[bi_][tid * 8]);                               \
    GL16(gk_ + 32 * DD,  &kbuf[bi_][2048 + tid * 8]);                        \
  } while (0)
#define SV(bi_, kvb_) do {                                                   \
    const unsigned short* gv_ = Vt + (size_t)krow0 * TT + (kvb_) + chx * 8;  \
    GL16(gv_,            &vbuf[bi_][tid * 8]);                               \
    GL16(gv_ + 32 * TT,  &vbuf[bi_][2048 + tid * 8]);                        \
  } while (0)

  const int qw = g * 128 + wid * 32;
  const int q = qw + l31;                // this lane's q row
  const int nt = 2 * (g + 1);            // kv-64 tiles for the block
  const int ntw = (qw >> 6) + 1;         // tiles this wave actually needs

  bf16x8 qf[4];
  #pragma unroll
  for (int c = 0; c < 4; ++c)
    qf[c] = *reinterpret_cast<const bf16x8*>(&Q[(size_t)q * DD + c * 16 + h * 8]);

  f32x16 y0 = zero16(), y1 = zero16();
  float lp = 0.f;

  SK(0, 0);
  SV(0, 0);
  SK(1, 64);                             // nt >= 2 always
  SV(1, 64);
  asm volatile("s_waitcnt vmcnt(4)" ::: "memory");
  __builtin_amdgcn_s_barrier();

  for (int t = 0; t < nt; ++t) {
    const unsigned short* sK = kbuf[t & 1];
    const unsigned short* sV = vbuf[t & 1];

    if (t < ntw) {
      const int kvb = t * 64;

      // ---- QK: S^T[kv 0-31][q] -> z0, [kv 32-63][q] -> z1 ----
      f32x16 z0 = zero16(), z1 = zero16();
      __builtin_amdgcn_s_setprio(1);
      #pragma unroll
      for (int c = 0; c < 4; ++c) {
        bf16x8 kf = *reinterpret_cast<const bf16x8*>(
            &sK[l31 * 64 + (((2 * c + h) ^ lx)) * 8]);
        z0 = mfma32(kf, qf[c], z0);
      }
      #pragma unroll
      for (int c = 0; c < 4; ++c) {
        bf16x8 kf = *reinterpret_cast<const bf16x8*>(
            &sK[(32 + l31) * 64 + (((2 * c + h) ^ lx)) * 8]);
        z1 = mfma32(kf, qf[c], z1);
      }
      __builtin_amdgcn_s_setprio(0);

      // ---- causal mask (only this wave's last tile) ----
      if (t == ntw - 1) {
        #pragma unroll
        for (int r = 0; r < 16; ++r) {
          const int kv0 = kvb + (r & 3) + 8 * (r >> 2) + 4 * h;
          if (kv0 > q) z0[r] = -1e30f;
          if (kv0 + 32 > q) z1[r] = -1e30f;
        }
      }

      // ---- m = 0 softmax: P = exp2(z) directly; per-lane partial sum ----
      float sq[8];
      #pragma unroll
      for (int i = 0; i < 4; ++i) {
        #pragma unroll
        for (int r = 0; r < 4; ++r) {
          z0[4 * i + r] = exp2f(z0[4 * i + r]);
          z1[4 * i + r] = exp2f(z1[4 * i + r]);
        }
        sq[i] = (z0[4 * i] + z0[4 * i + 1]) + (z0[4 * i + 2] + z0[4 * i + 3]);
        sq[4 + i] = (z1[4 * i] + z1[4 * i + 1]) + (z1[4 * i + 2] + z1[4 * i + 3]);
      }
      lp += ((sq[0] + sq[1]) + (sq[2] + sq[3])) +
            ((sq[4] + sq[5]) + (sq[6] + sq[7]));

      // ---- pack P to bf16 words; build PV B-frags via permlane32_swap ----
      unsigned pw[16];
      #pragma unroll
      for (int w = 0; w < 8; ++w) {
        pw[w] = pack2(z0[2 * w], z0[2 * w + 1]);
        pw[8 + w] = pack2(z1[2 * w], z1[2 * w + 1]);
      }
      #pragma unroll
      for (int kb = 0; kb < 4; ++kb) {
        // vdst'[32:63] = vsrc[0:31]; vsrc'[0:31] = vdst[32:63]
        asm("v_permlane32_swap_b32 %0, %1"
            : "+v"(pw[4 * kb]), "+v"(pw[4 * kb + 2]));
        asm("v_permlane32_swap_b32 %0, %1"
            : "+v"(pw[4 * kb + 1]), "+v"(pw[4 * kb + 3]));
      }

      // ---- PV: Y^T[d][q] += V^T-tile x P^T ----
      __builtin_amdgcn_s_setprio(1);
      #pragma unroll
      for (int kb = 0; kb < 4; ++kb) {
        union { unsigned w[4]; bf16x8 v; } pf;
        pf.w[0] = pw[4 * kb];
        pf.w[1] = pw[4 * kb + 1];
        pf.w[2] = pw[4 * kb + 2];
        pf.w[3] = pw[4 * kb + 3];
        bf16x8 vf0 = *reinterpret_cast<const bf16x8*>(
            &sV[l31 * 64 + (((2 * kb + h) ^ lx)) * 8]);
        y0 = mfma32(vf0, pf.v, y0);
        bf16x8 vf1 = *reinterpret_cast<const bf16x8*>(
            &sV[(32 + l31) * 64 + (((2 * kb + h) ^ lx)) * 8]);
        y1 = mfma32(vf1, pf.v, y1);
      }
      __builtin_amdgcn_s_setprio(0);
    }

    __syncthreads();  // all waves done with buf[t&1]; drains in-flight loads
    if (t + 2 < nt) {
      SK(t & 1, (t + 2) * 64);
      SV(t & 1, (t + 2) * 64);
    }
  }

  // ---- epilogue: reduce l across the q-lane pair; write Y ----
  lp += __shfl_xor(lp, 32);
  const float rl = 1.0f / lp;
  const size_t obase = ((size_t)b * TT + q) * CCH + hd * DD;
  #pragma unroll
  for (int g4 = 0; g4 < 4; ++g4) {
    const int d0 = 8 * g4 + 4 * h;
    unsigned w0 = pack2(y0[4 * g4] * rl, y0[4 * g4 + 1] * rl);
    unsigned w1 = pack2(y0[4 * g4 + 2] * rl, y0[4 * g4 + 3] * rl);
    *reinterpret_cast<uint2*>(&yb[obase + d0]) = make_uint2(w0, w1);
    unsigned w2 = pack2(y1[4 * g4] * rl, y1[4 * g4 + 1] * rl);
    unsigned w3 = pack2(y1[4 * g4 + 2] * rl, y1[4 * g4 + 3] * rl);
    *reinterpret_cast<uint2*>(&yb[obase + 32 + d0]) = make_uint2(w2, w3);
  }
#undef SK
#undef SV
}

// ---------------- launcher ----------------

extern "C" void kernel_launch(void* const* d_in, const int* in_sizes, int n_in,
                              void* d_out, int out_size, void* d_ws, size_t ws_size,
                              hipStream_t stream) {
  const float* x      = (const float*)d_in[0];
  const float* w_attn = (const float*)d_in[1];
  const float* b_attn = (const float*)d_in[2];
  const float* w_proj = (const float*)d_in[3];
  const float* b_proj = (const float*)d_in[4];
  float* out = (float*)d_out;
  char* ws = (char*)d_ws;

  unsigned short* xb  = (unsigned short*)(ws + 0);          // 16 MB
  unsigned short* wat = (unsigned short*)(ws + 16777216);   // 6 MB  [3072][1024]
  unsigned short* wpt = (unsigned short*)(ws + 23068672);   // 2 MB  [1024][1024]
  unsigned short* qb  = (unsigned short*)(ws + 25165824);   // 16 MB [B,H,T,D]
  unsigned short* kb  = (unsigned short*)(ws + 41943040);   // 16 MB [B,H,T,D]
  unsigned short* vt  = (unsigned short*)(ws + 58720256);   // 16 MB [B,H,D,T]
  unsigned short* yb  = (unsigned short*)(ws + 75497472);   // 16 MB [B,T,C]

  cvt_f32_bf16<<<(8192 * 1024 / 4 + 255) / 256, 256, 0, stream>>>(x, xb, 8192 * 1024 / 4);
  transpose_cvt<<<dim3(3072 / 32, 32), 256, 0, stream>>>(w_attn, wat, 3072);
  transpose_cvt<<<dim3(1024 / 32, 32), 256, 0, stream>>>(w_proj, wpt, 1024);

  // QKV GEMM: 64 m-blocks x 24 n-blocks = 1536 wg; wpx = 192
  gemm_bf16<0><<<1536, 256, 0, stream>>>(
      xb, wat, b_attn, nullptr, qb, kb, vt, 24, 192);

  attn_kernel<<<1024, 256, 0, stream>>>(qb, kb, vt, yb);

  // proj GEMM: 64 m-blocks x 8 n-blocks = 512 wg; wpx = 64
  gemm_bf16<1><<<512, 256, 0, stream>>>(
      yb, wpt, b_proj, out, nullptr, nullptr, nullptr, 8, 64);
}